// Round 1
// baseline (357.180 us; speedup 1.0000x reference)
//
#include <hip/hip_runtime.h>
#include <hip/hip_bf16.h>
#include <cstdint>
#include <cstddef>

// Problem: x,y [8192,512] fp32. Column-normalize (axis=0, ddof=1),
// out[n,m] = exp(-max(||xn_n||^2 + ||yn_m||^2 - 2 xn_n.yn_m, 0)), fp32 [8192,8192].

#define NR 8192
#define NC 512
#define EPSV 1e-8f

typedef __attribute__((ext_vector_type(8))) short bf16x8;
typedef __attribute__((ext_vector_type(4))) float f32x4;

// round-to-nearest-even f32 -> bf16 bits
__device__ __forceinline__ unsigned short f2bf(float f) {
  unsigned int u = __float_as_uint(f);
  u += 0x7FFFu + ((u >> 16) & 1u);
  return (unsigned short)(u >> 16);
}

__device__ __forceinline__ void gl_lds16(const unsigned short* g, unsigned short* l) {
  __builtin_amdgcn_global_load_lds(
      (const __attribute__((address_space(1))) void*)g,
      (__attribute__((address_space(3))) void*)l, 16, 0, 0);
}

// ---------------- stage 1: per-column partial sums ----------------
// grid (32 chunks, 2 inputs), 256 threads; thread t owns columns 2t, 2t+1
__global__ void __launch_bounds__(256) colstats_partial(
    const float* __restrict__ x, const float* __restrict__ y,
    float* __restrict__ part) {
  const int input = blockIdx.y;
  const int chunk = blockIdx.x;
  const float* in = input ? y : x;
  const int t = threadIdx.x;
  float sx = 0.f, sy = 0.f, qx = 0.f, qy = 0.f;
  const float* p = in + (size_t)chunk * 256 * NC + 2 * t;
  for (int r = 0; r < 256; ++r) {
    float2 v = *(const float2*)p;
    sx += v.x; sy += v.y;
    qx += v.x * v.x; qy += v.y * v.y;
    p += NC;
  }
  float* o = part + (size_t)(input * 32 + chunk) * 1024;
  o[2 * t] = sx; o[2 * t + 1] = sy;
  o[512 + 2 * t] = qx; o[512 + 2 * t + 1] = qy;
}

// ---------------- stage 2: finalize mean / 1/(std+eps) ----------------
// grid (2 inputs), 512 threads (one per column)
__global__ void __launch_bounds__(512) colstats_final(
    const float* __restrict__ part, float* __restrict__ mean,
    float* __restrict__ inv) {
  const int input = blockIdx.x;
  const int c = threadIdx.x;
  float s = 0.f, q = 0.f;
  for (int k = 0; k < 32; ++k) {
    const float* p = part + (size_t)(input * 32 + k) * 1024;
    s += p[c];
    q += p[512 + c];
  }
  float m = s / (float)NR;
  float var = (q - (float)NR * m * m) / (float)(NR - 1);
  var = fmaxf(var, 0.f);
  mean[input * NC + c] = m;
  inv[input * NC + c] = 1.f / (sqrtf(var) + EPSV);
}

// ---------------- stage 3: normalize, cast bf16, row sq-norms ----------------
// grid (2048, 2 inputs), 256 threads = 4 waves, one row per wave
__global__ void __launch_bounds__(256) normalize_rows(
    const float* __restrict__ x, const float* __restrict__ y,
    const float* __restrict__ mean, const float* __restrict__ inv,
    unsigned short* __restrict__ xn, unsigned short* __restrict__ yn,
    float* __restrict__ x2, float* __restrict__ y2) {
  const int input = blockIdx.y;
  const float* in = input ? y : x;
  unsigned short* outn = input ? yn : xn;
  float* out2 = input ? y2 : x2;
  const float* mu = mean + input * NC;
  const float* iv = inv + input * NC;
  const int wave = threadIdx.x >> 6, lane = threadIdx.x & 63;
  const int row = blockIdx.x * 4 + wave;
  float ss = 0.f;
#pragma unroll
  for (int it = 0; it < 2; ++it) {
    const int c = it * 256 + lane * 4;
    float4 v = *(const float4*)(in + (size_t)row * NC + c);
    float4 m4 = *(const float4*)(mu + c);
    float4 i4 = *(const float4*)(iv + c);
    float a = (v.x - m4.x) * i4.x;
    float b = (v.y - m4.y) * i4.y;
    float cc = (v.z - m4.z) * i4.z;
    float d = (v.w - m4.w) * i4.w;
    ss += a * a + b * b + cc * cc + d * d;
    ushort4 pk = make_ushort4(f2bf(a), f2bf(b), f2bf(cc), f2bf(d));
    *(ushort4*)(outn + (size_t)row * NC + c) = pk;
  }
#pragma unroll
  for (int off = 32; off > 0; off >>= 1) ss += __shfl_down(ss, off);
  if (lane == 0) out2[row] = ss;
}

// ---------------- stage 4: bf16 MFMA GEMM + RBF epilogue ----------------
// 128x128 C-tile per 256-thread block, 4 waves in 2x2, each wave 4x4 of
// 16x16x32 MFMA. BK=64, global_load_lds width=16, 2-barrier K-loop (m97).
__global__ void __launch_bounds__(256, 2) rbf_gemm(
    const unsigned short* __restrict__ xn, const unsigned short* __restrict__ yn,
    const float* __restrict__ x2, const float* __restrict__ y2,
    float* __restrict__ out) {
  __shared__ unsigned short As[128 * 64];
  __shared__ unsigned short Bs[128 * 64];
  const int tid = threadIdx.x;
  const int w = tid >> 6, lane = tid & 63;
  const int wr = w >> 1, wc = w & 1;
  const int by = blockIdx.y, bx = blockIdx.x;

  f32x4 acc[4][4] = {};

  const unsigned short* gA = xn + (size_t)by * 128 * NC;
  const unsigned short* gB = yn + (size_t)bx * 128 * NC;

  for (int k0 = 0; k0 < NC; k0 += 64) {
    // stage A,B tiles: each wave issues 4+4 16B-per-lane load_lds
#pragma unroll
    for (int j = 0; j < 4; ++j) {
      const int chunk = (w * 4 + j) * 64 + lane;  // 0..1023 16B chunks
      const int row = chunk >> 3;                 // tile row 0..127
      const int cc = (chunk & 7) * 8;             // bf16 col within BK
      gl_lds16(gA + (size_t)row * NC + k0 + cc, &As[chunk * 8]);
      gl_lds16(gB + (size_t)row * NC + k0 + cc, &Bs[chunk * 8]);
    }
    __syncthreads();  // drains vmcnt -> LDS valid
    const int m16 = lane & 15, quad = lane >> 4;
#pragma unroll
    for (int kk = 0; kk < 2; ++kk) {
      bf16x8 af[4], bfr[4];
      const int kc = kk * 32 + quad * 8;
#pragma unroll
      for (int i = 0; i < 4; ++i)
        af[i] = *(const bf16x8*)&As[(wr * 64 + i * 16 + m16) * 64 + kc];
#pragma unroll
      for (int j = 0; j < 4; ++j)
        bfr[j] = *(const bf16x8*)&Bs[(wc * 64 + j * 16 + m16) * 64 + kc];
#pragma unroll
      for (int i = 0; i < 4; ++i)
#pragma unroll
        for (int j = 0; j < 4; ++j)
          acc[i][j] = __builtin_amdgcn_mfma_f32_16x16x32_bf16(
              af[i], bfr[j], acc[i][j], 0, 0, 0);
    }
    __syncthreads();  // all reads done before next overwrite
  }

  // epilogue: C/D layout col=lane&15, row=(lane>>4)*4+reg
  const int col = lane & 15, quad = lane >> 4;
#pragma unroll
  for (int i = 0; i < 4; ++i) {
    const int n0 = by * 128 + wr * 64 + i * 16 + quad * 4;
#pragma unroll
    for (int j = 0; j < 4; ++j) {
      const int m = bx * 128 + wc * 64 + j * 16 + col;
      const float y2v = y2[m];
#pragma unroll
      for (int r = 0; r < 4; ++r) {
        const int n = n0 + r;
        const float d = x2[n] + y2v - 2.f * acc[i][j][r];
        out[(size_t)n * NR + m] = __expf(-fmaxf(d, 0.f));
      }
    }
  }
}

extern "C" void kernel_launch(void* const* d_in, const int* in_sizes, int n_in,
                              void* d_out, int out_size, void* d_ws, size_t ws_size,
                              hipStream_t stream) {
  const float* x = (const float*)d_in[0];
  const float* y = (const float*)d_in[1];
  float* out = (float*)d_out;
  char* ws = (char*)d_ws;

  // ws layout: xn[8MB] | yn[8MB] | x2[32KB] | y2[32KB] | mean/inv[8KB] | part[256KB]
  unsigned short* xn = (unsigned short*)ws;
  unsigned short* yn = xn + (size_t)NR * NC;
  float* x2 = (float*)(ws + (size_t)16 * 1024 * 1024);
  float* y2 = x2 + NR;
  float* mean = y2 + NR;
  float* inv = mean + 1024;
  float* part = inv + 1024;

  colstats_partial<<<dim3(32, 2), 256, 0, stream>>>(x, y, part);
  colstats_final<<<dim3(2), 512, 0, stream>>>(part, mean, inv);
  normalize_rows<<<dim3(2048, 2), 256, 0, stream>>>(x, y, mean, inv, xn, yn, x2, y2);
  rbf_gemm<<<dim3(64, 64), 256, 0, stream>>>(xn, yn, x2, y2, out);
}